// Round 2
// baseline (390.302 us; speedup 1.0000x reference)
//
#include <hip/hip_runtime.h>
#include <stdint.h>

// ---- problem constants ----
#define Tn   2048
#define Cn   1024
#define NHn  16
#define Hn   64
#define FFn  3072
#define Mrows 4096           // B*T
#define LNEPS 1e-6f

typedef float f32x4 __attribute__((ext_vector_type(4)));
typedef __bf16 bf16x8 __attribute__((ext_vector_type(8)));
typedef unsigned short us8 __attribute__((ext_vector_type(8)));
typedef unsigned short us4 __attribute__((ext_vector_type(4)));

__device__ __forceinline__ unsigned short f2bf(float f) {
    return __builtin_bit_cast(unsigned short, (__bf16)f);
}

__device__ __forceinline__ void gl_lds16(const void* g, void* l) {
    __builtin_amdgcn_global_load_lds(
        (const __attribute__((address_space(1))) void*)g,
        (__attribute__((address_space(3))) void*)l, 16, 0, 0);
}

// ---------------- weight prep ----------------
// Wq/Wk/Wv: [NH][C][H] f32  ->  wqkv_t [3072][1024] bf16 (row n = output chan, col = c)
__global__ __launch_bounds__(256) void cast_qkv_kernel(
    const float* __restrict__ Wq, const float* __restrict__ Wk,
    const float* __restrict__ Wv, unsigned short* __restrict__ out)
{
    int idx = blockIdx.x * 256 + threadIdx.x;          // 3072*1024 total
    int n = idx >> 10, cc = idx & 1023;
    const float* W = (n < 1024) ? Wq : ((n < 2048) ? Wk : Wv);
    int nn = n & 1023;
    float v = W[(size_t)((nn >> 6) * 1024 + cc) * 64 + (nn & 63)];
    out[idx] = f2bf(v);
}

__global__ __launch_bounds__(256) void cast_w_kernel(
    const float* __restrict__ src, unsigned short* __restrict__ dst, int count)
{
    int idx = blockIdx.x * 256 + threadIdx.x;
    if (idx < count) dst[idx] = f2bf(src[idx]);
}

// ---------------- layernorm (torch: ddof=1, eps on std) ----------------
__global__ __launch_bounds__(256) void ln_kernel(
    const float* __restrict__ xin, const float* __restrict__ gamma,
    const float* __restrict__ beta, unsigned short* __restrict__ out)
{
    const int row = blockIdx.x;
    const int tid = threadIdx.x;
    const float4 v = ((const float4*)(xin + (size_t)row * Cn))[tid];
    float s  = v.x + v.y + v.z + v.w;
    float ss = v.x*v.x + v.y*v.y + v.z*v.z + v.w*v.w;
    #pragma unroll
    for (int off = 1; off < 64; off <<= 1) {
        s  += __shfl_xor(s, off);
        ss += __shfl_xor(ss, off);
    }
    __shared__ float red[8];
    const int wave = tid >> 6, lane = tid & 63;
    if (lane == 0) { red[wave] = s; red[4 + wave] = ss; }
    __syncthreads();
    float S  = red[0] + red[1] + red[2] + red[3];
    float SS = red[4] + red[5] + red[6] + red[7];
    float mean = S * (1.0f / 1024.0f);
    float var  = (SS - 1024.0f * mean * mean) * (1.0f / 1023.0f);
    var = fmaxf(var, 0.0f);
    float inv = 1.0f / (sqrtf(var) + LNEPS);
    const float4 gv = ((const float4*)gamma)[tid];
    const float4 bv = ((const float4*)beta)[tid];
    us4 ov;
    ov[0] = f2bf(gv.x * (v.x - mean) * inv + bv.x);
    ov[1] = f2bf(gv.y * (v.y - mean) * inv + bv.y);
    ov[2] = f2bf(gv.z * (v.z - mean) * inv + bv.z);
    ov[3] = f2bf(gv.w * (v.w - mean) * inv + bv.w);
    *(us4*)(out + (size_t)row * Cn + tid * 4) = ov;
}

// ---------------- GEMM: C[M][N] = A[M][K] * Bt[N][K]^T  (bf16 in, f32 acc) ----------------
// MODE 0: store bf16               (QKV)
// MODE 1: f32 store + bias + resid (out-proj, FF2)
// MODE 2: bf16 store + bias + relu (FF1)
template<int MODE>
__global__ __launch_bounds__(256) void gemm_bt(
    const unsigned short* __restrict__ A,
    const unsigned short* __restrict__ Bt,
    void* Cout,                      // may alias resid (FF2) -> no restrict
    const float* __restrict__ bias,
    const float* resid,
    int M, int N, int K)
{
    __shared__ unsigned short As[128 * 32];   // [row][k], 64B rows
    __shared__ unsigned short Bs[128 * 32];
    const int tid  = threadIdx.x;
    const int wave = tid >> 6, lane = tid & 63;
    const int g = lane >> 4, c = lane & 15;
    const int wr = wave >> 1, wc = wave & 1;
    const int m0 = blockIdx.x * 128, n0 = blockIdx.y * 128;

    f32x4 acc[4][4];
    #pragma unroll
    for (int i = 0; i < 4; i++)
        #pragma unroll
        for (int j = 0; j < 4; j++) acc[i][j] = (f32x4){0.f, 0.f, 0.f, 0.f};

    const unsigned short* gA = A  + (size_t)(m0 + (tid >> 2)) * K + (tid & 3) * 8;
    const unsigned short* gB = Bt + (size_t)(n0 + (tid >> 2)) * K + (tid & 3) * 8;
    unsigned short* lA = &As[wave * 512];     // per-wave 1KB region
    unsigned short* lB = &Bs[wave * 512];

    for (int k0 = 0; k0 < K; k0 += 32) {
        gl_lds16(gA + k0,                    lA);
        gl_lds16(gA + (size_t)64 * K + k0,   lA + 2048);
        gl_lds16(gB + k0,                    lB);
        gl_lds16(gB + (size_t)64 * K + k0,   lB + 2048);
        __syncthreads();
        bf16x8 af[4], bfr[4];
        #pragma unroll
        for (int mi = 0; mi < 4; mi++)
            af[mi]  = *(const bf16x8*)&As[(wr * 64 + mi * 16 + c) * 32 + g * 8];
        #pragma unroll
        for (int ni = 0; ni < 4; ni++)
            bfr[ni] = *(const bf16x8*)&Bs[(wc * 64 + ni * 16 + c) * 32 + g * 8];
        #pragma unroll
        for (int mi = 0; mi < 4; mi++)
            #pragma unroll
            for (int ni = 0; ni < 4; ni++)
                acc[mi][ni] = __builtin_amdgcn_mfma_f32_16x16x32_bf16(
                    af[mi], bfr[ni], acc[mi][ni], 0, 0, 0);
        __syncthreads();
    }

    const int rowb = m0 + wr * 64 + g * 4;
    const int colb = n0 + wc * 64 + c;
    #pragma unroll
    for (int mi = 0; mi < 4; mi++) {
        #pragma unroll
        for (int ni = 0; ni < 4; ni++) {
            const int col = colb + ni * 16;
            float bv = (MODE == 1 || MODE == 2) ? bias[col] : 0.f;
            #pragma unroll
            for (int r = 0; r < 4; r++) {
                const int row = rowb + mi * 16 + r;
                float v = acc[mi][ni][r];
                if (MODE == 1) {
                    float res = resid[(size_t)row * N + col];
                    ((float*)Cout)[(size_t)row * N + col] = v + bv + res;
                } else if (MODE == 2) {
                    float t = v + bv;
                    t = t > 0.f ? t : 0.f;
                    ((unsigned short*)Cout)[(size_t)row * N + col] = f2bf(t);
                } else {
                    ((unsigned short*)Cout)[(size_t)row * N + col] = f2bf(v);
                }
            }
        }
    }
}

// ---------------- V transpose: qkv v-part [b][t][h*64+d] -> vt[bh][d][t] ----------------
__global__ __launch_bounds__(256) void transpose_v_kernel(
    const unsigned short* __restrict__ qkv, unsigned short* __restrict__ vt)
{
    __shared__ unsigned short tile[64][72];   // pitch 144B, 16B-aligned rows
    const int bh = blockIdx.y;
    const int b = bh >> 4, h = bh & 15;
    const int t0 = blockIdx.x * 64;
    const int tid = threadIdx.x;
    const int tr = tid >> 2;               // t-row 0..63
    const int dc = (tid & 3) * 16;         // d-col block
    const unsigned short* src =
        qkv + (size_t)(b * Tn + t0 + tr) * 3072 + 2048 + h * 64 + dc;
    *(us8*)&tile[tr][dc]     = *(const us8*)src;
    *(us8*)&tile[tr][dc + 8] = *(const us8*)(src + 8);
    __syncthreads();
    const int dr = tid >> 2;               // d-row 0..63
    const int tc = (tid & 3) * 16;         // t-col block
    unsigned short* dst = vt + (size_t)bh * Hn * Tn + (size_t)dr * Tn + t0 + tc;
    us8 o0, o1;
    #pragma unroll
    for (int e = 0; e < 8; e++) o0[e] = tile[tc + e][dr];
    #pragma unroll
    for (int e = 0; e < 8; e++) o1[e] = tile[tc + 8 + e][dr];
    *(us8*)dst       = o0;
    *(us8*)(dst + 8) = o1;
}

// ---------------- flash attention ----------------
// qkv: [B][T][3072] bf16 (q | k | v); vt: [bh][64 d][2048 t] bf16; ctx: [B][T][1024] bf16
// 4 independent waves per block; wave w handles q-tile (w*32 + blockIdx.x), 16 rows.
__global__ __launch_bounds__(256) void attn_kernel(
    const unsigned short* __restrict__ qkv,
    const unsigned short* __restrict__ vt,
    unsigned short* __restrict__ ctx)
{
    const int tid = threadIdx.x;
    const int wave = tid >> 6, lane = tid & 63;
    const int g = lane >> 4, c = lane & 15;
    const int tileIdx = wave * 32 + blockIdx.x;   // equal total work per block
    const int t0 = tileIdx * 16;
    const int bh = blockIdx.y;
    const int b = bh >> 4, h = bh & 15;
    const unsigned short* base  = qkv + (size_t)b * Tn * 3072;
    const unsigned short* qbase = base + h * 64;
    const unsigned short* kbase = base + 1024 + h * 64;
    const unsigned short* vtb   = vt + (size_t)bh * Hn * Tn;

    bf16x8 qf[2];
    {
        const unsigned short* qp = qbase + (size_t)(t0 + c) * 3072 + g * 8;
        qf[0] = *(const bf16x8*)qp;
        qf[1] = *(const bf16x8*)(qp + 32);
    }

    float mrun[4], lrun[4];
    f32x4 o[4];
    #pragma unroll
    for (int r = 0; r < 4; r++) { mrun[r] = -1e30f; lrun[r] = 0.f; }
    #pragma unroll
    for (int nc = 0; nc < 4; nc++) o[nc] = (f32x4){0.f, 0.f, 0.f, 0.f};

    __shared__ unsigned short P[4][16 * 32];
    unsigned short* Pw = P[wave];

    for (int s0 = 0; s0 < t0 + 16; s0 += 32) {
        // ---- S = Q K^T (16x32 tile), rows 4g+r, cols sc*16+c ----
        f32x4 sacc[2];
        sacc[0] = (f32x4){0.f, 0.f, 0.f, 0.f};
        sacc[1] = (f32x4){0.f, 0.f, 0.f, 0.f};
        #pragma unroll
        for (int sc = 0; sc < 2; sc++) {
            const unsigned short* kp = kbase + (size_t)(s0 + sc * 16 + c) * 3072 + g * 8;
            sacc[sc] = __builtin_amdgcn_mfma_f32_16x16x32_bf16(
                qf[0], *(const bf16x8*)kp, sacc[sc], 0, 0, 0);
            sacc[sc] = __builtin_amdgcn_mfma_f32_16x16x32_bf16(
                qf[1], *(const bf16x8*)(kp + 32), sacc[sc], 0, 0, 0);
        }
        // ---- scale + causal mask + online softmax ----
        float pv[2][4], tmax[4];
        #pragma unroll
        for (int r = 0; r < 4; r++) {
            const int trow = t0 + g * 4 + r;
            float v0 = sacc[0][r] * 0.125f;
            float v1 = sacc[1][r] * 0.125f;
            if (s0 + c      > trow) v0 = -1e30f;
            if (s0 + 16 + c > trow) v1 = -1e30f;
            pv[0][r] = v0; pv[1][r] = v1;
            tmax[r] = fmaxf(v0, v1);
        }
        #pragma unroll
        for (int off = 1; off < 16; off <<= 1)
            #pragma unroll
            for (int r = 0; r < 4; r++)
                tmax[r] = fmaxf(tmax[r], __shfl_xor(tmax[r], off));
        float csum[4];
        #pragma unroll
        for (int r = 0; r < 4; r++) {
            float mnew = fmaxf(mrun[r], tmax[r]);
            float corr = __expf(mrun[r] - mnew);
            mrun[r] = mnew;
            float p0 = __expf(pv[0][r] - mnew);
            float p1 = __expf(pv[1][r] - mnew);
            pv[0][r] = p0; pv[1][r] = p1;
            lrun[r] *= corr;
            csum[r] = p0 + p1;
            #pragma unroll
            for (int nc = 0; nc < 4; nc++) o[nc][r] *= corr;
        }
        #pragma unroll
        for (int off = 1; off < 16; off <<= 1)
            #pragma unroll
            for (int r = 0; r < 4; r++)
                csum[r] += __shfl_xor(csum[r], off);
        #pragma unroll
        for (int r = 0; r < 4; r++) lrun[r] += csum[r];

        // ---- P -> LDS (per-wave buffer, same-wave ordering, no barrier) ----
        #pragma unroll
        for (int sc = 0; sc < 2; sc++)
            #pragma unroll
            for (int r = 0; r < 4; r++)
                Pw[(g * 4 + r) * 32 + sc * 16 + c] = f2bf(pv[sc][r]);
        bf16x8 pa = *(const bf16x8*)&Pw[c * 32 + g * 8];

        // ---- O += P V  (V^T rows: contiguous in s) ----
        #pragma unroll
        for (int nc = 0; nc < 4; nc++) {
            us8 tv = *(const us8*)(vtb + (size_t)(nc * 16 + c) * Tn + s0 + g * 8);
            o[nc] = __builtin_amdgcn_mfma_f32_16x16x32_bf16(
                pa, __builtin_bit_cast(bf16x8, tv), o[nc], 0, 0, 0);
        }
    }

    #pragma unroll
    for (int nc = 0; nc < 4; nc++)
        #pragma unroll
        for (int r = 0; r < 4; r++) {
            const int trow = t0 + g * 4 + r;
            float val = o[nc][r] / lrun[r];
            ctx[(size_t)(b * Tn + trow) * 1024 + h * 64 + nc * 16 + c] = f2bf(val);
        }
}

// ---------------- launch ----------------
extern "C" void kernel_launch(void* const* d_in, const int* in_sizes, int n_in,
                              void* d_out, int out_size, void* d_ws, size_t ws_size,
                              hipStream_t stream) {
    const float* x   = (const float*)d_in[0];
    const float* Wq  = (const float*)d_in[1];
    const float* Wk  = (const float*)d_in[2];
    const float* Wv  = (const float*)d_in[3];
    const float* Wo  = (const float*)d_in[4];
    const float* bo  = (const float*)d_in[5];
    const float* W1  = (const float*)d_in[6];
    const float* b1  = (const float*)d_in[7];
    const float* W2  = (const float*)d_in[8];
    const float* b2  = (const float*)d_in[9];
    const float* g1  = (const float*)d_in[10];
    const float* be1 = (const float*)d_in[11];
    const float* g2  = (const float*)d_in[12];
    const float* be2 = (const float*)d_in[13];

    char* ws = (char*)d_ws;
    unsigned short* wqkv = (unsigned short*)ws;  ws += (size_t)3072 * 1024 * 2;
    unsigned short* wo   = (unsigned short*)ws;  ws += (size_t)1024 * 1024 * 2;
    unsigned short* w1   = (unsigned short*)ws;  ws += (size_t)3072 * 1024 * 2;
    unsigned short* w2   = (unsigned short*)ws;  ws += (size_t)1024 * 3072 * 2;
    unsigned short* bufA = (unsigned short*)ws;  ws += (size_t)Mrows * 1024 * 2; // xn1 / ctx / h2
    unsigned short* bufB = (unsigned short*)ws;  ws += (size_t)Mrows * 3072 * 2; // qkv / ffh

    float* xout = (float*)d_out;           // x1 lives here after out-proj
    // d_out is dead until out-proj -> park V^T there (8 MB of its 16 MB)
    unsigned short* vt = (unsigned short*)d_out;

    // weight prep
    cast_qkv_kernel<<<12288, 256, 0, stream>>>(Wq, Wk, Wv, wqkv);
    cast_w_kernel<<<4096, 256, 0, stream>>>(Wo, wo, 1024 * 1024);
    cast_w_kernel<<<12288, 256, 0, stream>>>(W1, w1, 3072 * 1024);
    cast_w_kernel<<<12288, 256, 0, stream>>>(W2, w2, 1024 * 3072);

    // xn1 = LN(x)
    ln_kernel<<<Mrows, 256, 0, stream>>>(x, g1, be1, bufA);
    // qkv = xn1 @ Wqkv^T
    gemm_bt<0><<<dim3(32, 24), 256, 0, stream>>>(bufA, wqkv, bufB, nullptr, nullptr,
                                                 Mrows, 3072, 1024);
    // vt = V^T
    transpose_v_kernel<<<dim3(Tn / 64, 2 * NHn), 256, 0, stream>>>(bufB, vt);
    // ctx = attention(qkv, vt)
    attn_kernel<<<dim3(32, 2 * NHn), 256, 0, stream>>>(bufB, vt, bufA);
    // x1 = x + ctx @ Wo^T + bo   (f32, into d_out; vt no longer needed)
    gemm_bt<1><<<dim3(32, 8), 256, 0, stream>>>(bufA, wo, xout, bo, x,
                                                Mrows, 1024, 1024);
    // h2 = LN(x1)
    ln_kernel<<<Mrows, 256, 0, stream>>>(xout, g2, be2, bufA);
    // ffh = relu(h2 @ W1^T + b1)
    gemm_bt<2><<<dim3(32, 24), 256, 0, stream>>>(bufA, w1, bufB, b1, nullptr,
                                                 Mrows, 3072, 1024);
    // out = x1 + ffh @ W2^T + b2  (in-place residual from d_out)
    gemm_bt<1><<<dim3(32, 8), 256, 0, stream>>>(bufB, w2, xout, b2, (const float*)xout,
                                                Mrows, 1024, 3072);
}

// Round 4
// 325.559 us; speedup vs baseline: 1.1989x; 1.1989x over previous
//
#include <hip/hip_runtime.h>
#include <stdint.h>

// ---- problem constants ----
#define Tn   2048
#define Cn   1024
#define NHn  16
#define Hn   64
#define FFn  3072
#define Mrows 4096           // B*T
#define LNEPS 1e-6f

typedef float f32x4 __attribute__((ext_vector_type(4)));
typedef __bf16 bf16x8 __attribute__((ext_vector_type(8)));
typedef unsigned short us8 __attribute__((ext_vector_type(8)));
typedef unsigned short us4 __attribute__((ext_vector_type(4)));
typedef unsigned int u32x4 __attribute__((ext_vector_type(4)));

__device__ __forceinline__ unsigned short f2bf(float f) {
    return __builtin_bit_cast(unsigned short, (__bf16)f);
}

__device__ __forceinline__ uint32_t pk2bf(float lo, float hi) {
    return (uint32_t)f2bf(lo) | ((uint32_t)f2bf(hi) << 16);
}

__device__ __forceinline__ void gl_lds16(const void* g, void* l) {
    __builtin_amdgcn_global_load_lds(
        (const __attribute__((address_space(1))) void*)g,
        (__attribute__((address_space(3))) void*)l, 16, 0, 0);
}

// ---------------- weight prep ----------------
__global__ __launch_bounds__(256) void cast_qkv_kernel(
    const float* __restrict__ Wq, const float* __restrict__ Wk,
    const float* __restrict__ Wv, unsigned short* __restrict__ out)
{
    int idx = blockIdx.x * 256 + threadIdx.x;          // 3072*1024 total
    int n = idx >> 10, cc = idx & 1023;
    const float* W = (n < 1024) ? Wq : ((n < 2048) ? Wk : Wv);
    int nn = n & 1023;
    float v = W[(size_t)((nn >> 6) * 1024 + cc) * 64 + (nn & 63)];
    out[idx] = f2bf(v);
}

__global__ __launch_bounds__(256) void cast_w_kernel(
    const float* __restrict__ src, unsigned short* __restrict__ dst, int count)
{
    int idx = blockIdx.x * 256 + threadIdx.x;
    if (idx < count) dst[idx] = f2bf(src[idx]);
}

// ---------------- layernorm (torch: ddof=1, eps on std) ----------------
__global__ __launch_bounds__(256) void ln_kernel(
    const float* __restrict__ xin, const float* __restrict__ gamma,
    const float* __restrict__ beta, unsigned short* __restrict__ out)
{
    const int row = blockIdx.x;
    const int tid = threadIdx.x;
    const float4 v = ((const float4*)(xin + (size_t)row * Cn))[tid];
    float s  = v.x + v.y + v.z + v.w;
    float ss = v.x*v.x + v.y*v.y + v.z*v.z + v.w*v.w;
    #pragma unroll
    for (int off = 1; off < 64; off <<= 1) {
        s  += __shfl_xor(s, off);
        ss += __shfl_xor(ss, off);
    }
    __shared__ float red[8];
    const int wave = tid >> 6, lane = tid & 63;
    if (lane == 0) { red[wave] = s; red[4 + wave] = ss; }
    __syncthreads();
    float S  = red[0] + red[1] + red[2] + red[3];
    float SS = red[4] + red[5] + red[6] + red[7];
    float mean = S * (1.0f / 1024.0f);
    float var  = (SS - 1024.0f * mean * mean) * (1.0f / 1023.0f);
    var = fmaxf(var, 0.0f);
    float inv = 1.0f / (sqrtf(var) + LNEPS);
    const float4 gv = ((const float4*)gamma)[tid];
    const float4 bv = ((const float4*)beta)[tid];
    us4 ov;
    ov[0] = f2bf(gv.x * (v.x - mean) * inv + bv.x);
    ov[1] = f2bf(gv.y * (v.y - mean) * inv + bv.y);
    ov[2] = f2bf(gv.z * (v.z - mean) * inv + bv.z);
    ov[3] = f2bf(gv.w * (v.w - mean) * inv + bv.w);
    *(us4*)(out + (size_t)row * Cn + tid * 4) = ov;
}

// ---------------- GEMM: C[M][N] = A[M][K] * Bt[N][K]^T  (bf16 in, f32 acc) ----------------
template<int MODE>
__global__ __launch_bounds__(256) void gemm_bt(
    const unsigned short* __restrict__ A,
    const unsigned short* __restrict__ Bt,
    void* Cout,
    const float* __restrict__ bias,
    const float* resid,
    int M, int N, int K)
{
    __shared__ unsigned short As[128 * 32];
    __shared__ unsigned short Bs[128 * 32];
    const int tid  = threadIdx.x;
    const int wave = tid >> 6, lane = tid & 63;
    const int g = lane >> 4, c = lane & 15;
    const int wr = wave >> 1, wc = wave & 1;
    const int m0 = blockIdx.x * 128, n0 = blockIdx.y * 128;

    f32x4 acc[4][4];
    #pragma unroll
    for (int i = 0; i < 4; i++)
        #pragma unroll
        for (int j = 0; j < 4; j++) acc[i][j] = (f32x4){0.f, 0.f, 0.f, 0.f};

    const unsigned short* gA = A  + (size_t)(m0 + (tid >> 2)) * K + (tid & 3) * 8;
    const unsigned short* gB = Bt + (size_t)(n0 + (tid >> 2)) * K + (tid & 3) * 8;
    unsigned short* lA = &As[wave * 512];
    unsigned short* lB = &Bs[wave * 512];

    for (int k0 = 0; k0 < K; k0 += 32) {
        gl_lds16(gA + k0,                    lA);
        gl_lds16(gA + (size_t)64 * K + k0,   lA + 2048);
        gl_lds16(gB + k0,                    lB);
        gl_lds16(gB + (size_t)64 * K + k0,   lB + 2048);
        __syncthreads();
        bf16x8 af[4], bfr[4];
        #pragma unroll
        for (int mi = 0; mi < 4; mi++)
            af[mi]  = *(const bf16x8*)&As[(wr * 64 + mi * 16 + c) * 32 + g * 8];
        #pragma unroll
        for (int ni = 0; ni < 4; ni++)
            bfr[ni] = *(const bf16x8*)&Bs[(wc * 64 + ni * 16 + c) * 32 + g * 8];
        #pragma unroll
        for (int mi = 0; mi < 4; mi++)
            #pragma unroll
            for (int ni = 0; ni < 4; ni++)
                acc[mi][ni] = __builtin_amdgcn_mfma_f32_16x16x32_bf16(
                    af[mi], bfr[ni], acc[mi][ni], 0, 0, 0);
        __syncthreads();
    }

    const int rowb = m0 + wr * 64 + g * 4;
    const int colb = n0 + wc * 64 + c;
    #pragma unroll
    for (int mi = 0; mi < 4; mi++) {
        #pragma unroll
        for (int ni = 0; ni < 4; ni++) {
            const int col = colb + ni * 16;
            float bv = (MODE == 1 || MODE == 2) ? bias[col] : 0.f;
            #pragma unroll
            for (int r = 0; r < 4; r++) {
                const int row = rowb + mi * 16 + r;
                float v = acc[mi][ni][r];
                if (MODE == 1) {
                    float res = resid[(size_t)row * N + col];
                    ((float*)Cout)[(size_t)row * N + col] = v + bv + res;
                } else if (MODE == 2) {
                    float t = v + bv;
                    t = t > 0.f ? t : 0.f;
                    ((unsigned short*)Cout)[(size_t)row * N + col] = f2bf(t);
                } else {
                    ((unsigned short*)Cout)[(size_t)row * N + col] = f2bf(v);
                }
            }
        }
    }
}

// ---------------- V transpose: qkv v-part [b][t][h*64+d] -> vt[bh][d][t] ----------------
__global__ __launch_bounds__(256) void transpose_v_kernel(
    const unsigned short* __restrict__ qkv, unsigned short* __restrict__ vt)
{
    __shared__ unsigned short tile[64][72];
    const int bh = blockIdx.y;
    const int b = bh >> 4, h = bh & 15;
    const int t0 = blockIdx.x * 64;
    const int tid = threadIdx.x;
    const int tr = tid >> 2;
    const int dc = (tid & 3) * 16;
    const unsigned short* src =
        qkv + (size_t)(b * Tn + t0 + tr) * 3072 + 2048 + h * 64 + dc;
    *(us8*)&tile[tr][dc]     = *(const us8*)src;
    *(us8*)&tile[tr][dc + 8] = *(const us8*)(src + 8);
    __syncthreads();
    const int dr = tid >> 2;
    const int tc = (tid & 3) * 16;
    unsigned short* dst = vt + (size_t)bh * Hn * Tn + (size_t)dr * Tn + t0 + tc;
    us8 o0, o1;
    #pragma unroll
    for (int e = 0; e < 8; e++) o0[e] = tile[tc + e][dr];
    #pragma unroll
    for (int e = 0; e < 8; e++) o1[e] = tile[tc + 8 + e][dr];
    *(us8*)dst       = o0;
    *(us8*)(dst + 8) = o1;
}

// ---------------- flash attention (swapped QK^T, no LDS, QBLK=32 KVBLK=64) ----------------
// qkv: [B][T][3072] bf16; vt: [bh][64 d][2048 t] bf16; ctx: [B][T][1024] bf16
// 4 waves/block, each wave owns a 32-row q-tile. Per KV chunk of 64:
//   S^T = mfma(Kfrag, Qfrag): lane(g,c) holds S[q=c][s=sc*16+4g+r]  (in-lane row softmax)
//   P redistributed to PV A-frag layout via cvt_pk + 32 shfl (derivation in comments).
__global__ __launch_bounds__(256, 2) void attn_kernel(
    const unsigned short* __restrict__ qkv,
    const unsigned short* __restrict__ vt,
    unsigned short* __restrict__ ctx)
{
    const int tid  = threadIdx.x;
    const int wave = tid >> 6, lane = tid & 63;
    const int g = lane >> 4, c = lane & 15;
    const int bx = blockIdx.x;                                  // 0..15
    const int tileIdx = wave * 16 + ((wave & 1) ? (15 - bx) : bx); // balanced pairing
    const int t0 = tileIdx * 32;
    const int bh = blockIdx.y;
    const int b = bh >> 4, h = bh & 15;
    const unsigned short* base  = qkv + (size_t)b * Tn * 3072;
    const unsigned short* qbase = base + h * 64;
    const unsigned short* kbase = base + 1024 + h * 64;
    const unsigned short* vtb   = vt + (size_t)bh * (Hn * Tn);

    // Q as MFMA B-operand: Q[q=t0+qa*16+c][d=kh*32+g*8+j]
    bf16x8 qf[2][2];
    #pragma unroll
    for (int qa = 0; qa < 2; qa++) {
        const unsigned short* qp = qbase + (size_t)(t0 + qa * 16 + c) * 3072 + g * 8;
        qf[qa][0] = *(const bf16x8*)qp;
        qf[qa][1] = *(const bf16x8*)(qp + 32);
    }

    float mrun[2] = {-1e30f, -1e30f};
    float lrun[2] = {0.f, 0.f};
    f32x4 o[2][4];
    #pragma unroll
    for (int qa = 0; qa < 2; qa++)
        #pragma unroll
        for (int nc = 0; nc < 4; nc++) o[qa][nc] = (f32x4){0.f, 0.f, 0.f, 0.f};

    for (int s0 = 0; s0 < t0 + 32; s0 += 64) {
        // K as MFMA A-operand: K[s=s0+sc*16+c][d=kh*32+g*8+j]
        bf16x8 kf[4][2];
        #pragma unroll
        for (int sc = 0; sc < 4; sc++) {
            const unsigned short* kp = kbase + (size_t)(s0 + sc * 16 + c) * 3072 + g * 8;
            kf[sc][0] = *(const bf16x8*)kp;
            kf[sc][1] = *(const bf16x8*)(kp + 32);
        }
        // V^T as MFMA B-operand: V[s=ks*32+g*8+j][d=nc*16+c]
        bf16x8 vf[4][2];
        #pragma unroll
        for (int nc = 0; nc < 4; nc++)
            #pragma unroll
            for (int ks = 0; ks < 2; ks++)
                vf[nc][ks] = *(const bf16x8*)(vtb + (size_t)(nc * 16 + c) * Tn
                                              + s0 + ks * 32 + g * 8);

        // S^T = K·Q^T : lane(g,c) -> S[q=c (tile qa)][s = sc*16 + 4g + r]
        f32x4 sacc[2][4];
        #pragma unroll
        for (int qa = 0; qa < 2; qa++)
            #pragma unroll
            for (int sc = 0; sc < 4; sc++) {
                f32x4 z = (f32x4){0.f, 0.f, 0.f, 0.f};
                z = __builtin_amdgcn_mfma_f32_16x16x32_bf16(kf[sc][0], qf[qa][0], z, 0, 0, 0);
                z = __builtin_amdgcn_mfma_f32_16x16x32_bf16(kf[sc][1], qf[qa][1], z, 0, 0, 0);
                sacc[qa][sc] = z;
            }

        uint32_t dw[2][4][2];
        #pragma unroll
        for (int qa = 0; qa < 2; qa++) {
            const int q = t0 + qa * 16 + c;
            float pm[4][4];
            const bool needMask = (s0 + 63 > t0 + qa * 16);
            #pragma unroll
            for (int sc = 0; sc < 4; sc++)
                #pragma unroll
                for (int r = 0; r < 4; r++) {
                    float v = sacc[qa][sc][r] * 0.125f;
                    if (needMask && (s0 + sc * 16 + 4 * g + r > q)) v = -1e30f;
                    pm[sc][r] = v;
                }
            // row max: serial 16 + 2 shfl (combine the 4 g-replicas of row q=c)
            float tmax = pm[0][0];
            #pragma unroll
            for (int sc = 0; sc < 4; sc++)
                #pragma unroll
                for (int r = 0; r < 4; r++) tmax = fmaxf(tmax, pm[sc][r]);
            tmax = fmaxf(tmax, __shfl_xor(tmax, 16));
            tmax = fmaxf(tmax, __shfl_xor(tmax, 32));
            float mnew = fmaxf(mrun[qa], tmax);
            float corr = __expf(mrun[qa] - mnew);
            mrun[qa] = mnew;
            float csum = 0.f;
            #pragma unroll
            for (int sc = 0; sc < 4; sc++)
                #pragma unroll
                for (int r = 0; r < 4; r++) {
                    float p = __expf(pm[sc][r] - mnew);
                    pm[sc][r] = p;
                    csum += p;
                }
            csum += __shfl_xor(csum, 16);
            csum += __shfl_xor(csum, 32);
            lrun[qa] = lrun[qa] * corr + csum;
            // rescale o rows: o-row (within qa) = 4g+r, stats live at lane c'=row
            float cb[4];
            #pragma unroll
            for (int r = 0; r < 4; r++) cb[r] = __shfl(corr, 4 * g + r);
            #pragma unroll
            for (int nc = 0; nc < 4; nc++)
                #pragma unroll
                for (int r = 0; r < 4; r++) o[qa][nc][r] *= cb[r];
            // pack P^T pairs: dw[qa][sc][h] = bf16x2(P[q=c][sc*16+4g+2h], [..+1])
            #pragma unroll
            for (int sc = 0; sc < 4; sc++) {
                dw[qa][sc][0] = pk2bf(pm[sc][0], pm[sc][1]);
                dw[qa][sc][1] = pk2bf(pm[sc][2], pm[sc][3]);
            }
        }

        // Redistribute P^T -> PV A-frag: target (g,c) dword jd needs
        //   s = ks*32 + 8g + 2jd(+1)  =  tile sc=2ks+(g>>1), src g'=2(g&1)+(jd>>1), dword jd&1
        #pragma unroll
        for (int ks = 0; ks < 2; ks++) {
            #pragma unroll
            for (int qa = 0; qa < 2; qa++) {
                u32x4 pd;
                #pragma unroll
                for (int jh = 0; jh < 2; jh++) {
                    const int srcLane = (2 * (g & 1) + jh) * 16 + c;
                    #pragma unroll
                    for (int hh = 0; hh < 2; hh++) {
                        int vA = __shfl((int)dw[qa][2 * ks][hh],     srcLane);
                        int vB = __shfl((int)dw[qa][2 * ks + 1][hh], srcLane);
                        pd[jh * 2 + hh] = (g < 2) ? (uint32_t)vA : (uint32_t)vB;
                    }
                }
                bf16x8 pa = __builtin_bit_cast(bf16x8, pd);
                #pragma unroll
                for (int nc = 0; nc < 4; nc++)
                    o[qa][nc] = __builtin_amdgcn_mfma_f32_16x16x32_bf16(
                        pa, vf[nc][ks], o[qa][nc], 0, 0, 0);
            }
        }
    }

    // epilogue: o rows = 4g+r within qa tile; 1/l broadcast from lane c'=row
    #pragma unroll
    for (int qa = 0; qa < 2; qa++) {
        float rl = 1.0f / lrun[qa];
        float lb[4];
        #pragma unroll
        for (int r = 0; r < 4; r++) lb[r] = __shfl(rl, 4 * g + r);
        #pragma unroll
        for (int nc = 0; nc < 4; nc++)
            #pragma unroll
            for (int r = 0; r < 4; r++) {
                const int trow = t0 + qa * 16 + 4 * g + r;
                ctx[(size_t)(b * Tn + trow) * 1024 + h * 64 + nc * 16 + c] =
                    f2bf(o[qa][nc][r] * lb[r]);
            }
    }
}

// ---------------- launch ----------------
extern "C" void kernel_launch(void* const* d_in, const int* in_sizes, int n_in,
                              void* d_out, int out_size, void* d_ws, size_t ws_size,
                              hipStream_t stream) {
    const float* x   = (const float*)d_in[0];
    const float* Wq  = (const float*)d_in[1];
    const float* Wk  = (const float*)d_in[2];
    const float* Wv  = (const float*)d_in[3];
    const float* Wo  = (const float*)d_in[4];
    const float* bo  = (const float*)d_in[5];
    const float* W1  = (const float*)d_in[6];
    const float* b1  = (const float*)d_in[7];
    const float* W2  = (const float*)d_in[8];
    const float* b2  = (const float*)d_in[9];
    const float* g1  = (const float*)d_in[10];
    const float* be1 = (const float*)d_in[11];
    const float* g2  = (const float*)d_in[12];
    const float* be2 = (const float*)d_in[13];

    char* ws = (char*)d_ws;
    unsigned short* wqkv = (unsigned short*)ws;  ws += (size_t)3072 * 1024 * 2;
    unsigned short* wo   = (unsigned short*)ws;  ws += (size_t)1024 * 1024 * 2;
    unsigned short* w1   = (unsigned short*)ws;  ws += (size_t)3072 * 1024 * 2;
    unsigned short* w2   = (unsigned short*)ws;  ws += (size_t)1024 * 3072 * 2;
    unsigned short* bufA = (unsigned short*)ws;  ws += (size_t)Mrows * 1024 * 2; // xn1 / ctx / h2
    unsigned short* bufB = (unsigned short*)ws;  ws += (size_t)Mrows * 3072 * 2; // qkv / ffh

    float* xout = (float*)d_out;           // x1 lives here after out-proj
    unsigned short* vt = (unsigned short*)d_out;   // V^T parks in dead d_out

    // weight prep
    cast_qkv_kernel<<<12288, 256, 0, stream>>>(Wq, Wk, Wv, wqkv);
    cast_w_kernel<<<4096, 256, 0, stream>>>(Wo, wo, 1024 * 1024);
    cast_w_kernel<<<12288, 256, 0, stream>>>(W1, w1, 3072 * 1024);
    cast_w_kernel<<<12288, 256, 0, stream>>>(W2, w2, 1024 * 3072);

    // xn1 = LN(x)
    ln_kernel<<<Mrows, 256, 0, stream>>>(x, g1, be1, bufA);
    // qkv = xn1 @ Wqkv^T
    gemm_bt<0><<<dim3(32, 24), 256, 0, stream>>>(bufA, wqkv, bufB, nullptr, nullptr,
                                                 Mrows, 3072, 1024);
    // vt = V^T
    transpose_v_kernel<<<dim3(Tn / 64, 2 * NHn), 256, 0, stream>>>(bufB, vt);
    // ctx = attention(qkv, vt)
    attn_kernel<<<dim3(16, 2 * NHn), 256, 0, stream>>>(bufB, vt, bufA);
    // x1 = x + ctx @ Wo^T + bo   (f32, into d_out; vt dead afterwards)
    gemm_bt<1><<<dim3(32, 8), 256, 0, stream>>>(bufA, wo, xout, bo, x,
                                                Mrows, 1024, 1024);
    // h2 = LN(x1)
    ln_kernel<<<Mrows, 256, 0, stream>>>(xout, g2, be2, bufA);
    // ffh = relu(h2 @ W1^T + b1)
    gemm_bt<2><<<dim3(32, 24), 256, 0, stream>>>(bufA, w1, bufB, b1, nullptr,
                                                 Mrows, 3072, 1024);
    // out = x1 + ffh @ W2^T + b2  (in-place residual from d_out)
    gemm_bt<1><<<dim3(32, 8), 256, 0, stream>>>(bufB, w2, xout, b2, (const float*)xout,
                                                Mrows, 1024, 3072);
}

// Round 5
// 295.626 us; speedup vs baseline: 1.3203x; 1.1013x over previous
//
#include <hip/hip_runtime.h>
#include <stdint.h>

// ---- problem constants ----
#define Tn   2048
#define Cn   1024
#define NHn  16
#define Hn   64
#define FFn  3072
#define Mrows 4096           // B*T
#define LNEPS 1e-6f

typedef float f32x4 __attribute__((ext_vector_type(4)));
typedef __bf16 bf16x8 __attribute__((ext_vector_type(8)));
typedef unsigned short us8 __attribute__((ext_vector_type(8)));
typedef unsigned short us4 __attribute__((ext_vector_type(4)));
typedef unsigned int u32x4 __attribute__((ext_vector_type(4)));

__device__ __forceinline__ unsigned short f2bf(float f) {
    return __builtin_bit_cast(unsigned short, (__bf16)f);
}

__device__ __forceinline__ uint32_t pk2bf(float lo, float hi) {
    return (uint32_t)f2bf(lo) | ((uint32_t)f2bf(hi) << 16);
}

__device__ __forceinline__ void gl_lds16(const void* g, void* l) {
    __builtin_amdgcn_global_load_lds(
        (const __attribute__((address_space(1))) void*)g,
        (__attribute__((address_space(3))) void*)l, 16, 0, 0);
}

// ---------------- weight prep ----------------
__global__ __launch_bounds__(256) void cast_qkv_kernel(
    const float* __restrict__ Wq, const float* __restrict__ Wk,
    const float* __restrict__ Wv, unsigned short* __restrict__ out)
{
    int idx = blockIdx.x * 256 + threadIdx.x;          // 3072*1024 total
    int n = idx >> 10, cc = idx & 1023;
    const float* W = (n < 1024) ? Wq : ((n < 2048) ? Wk : Wv);
    int nn = n & 1023;
    float v = W[(size_t)((nn >> 6) * 1024 + cc) * 64 + (nn & 63)];
    out[idx] = f2bf(v);
}

__global__ __launch_bounds__(256) void cast_w_kernel(
    const float* __restrict__ src, unsigned short* __restrict__ dst, int count)
{
    int idx = blockIdx.x * 256 + threadIdx.x;
    if (idx < count) dst[idx] = f2bf(src[idx]);
}

// ---------------- layernorm (torch: ddof=1, eps on std) ----------------
__global__ __launch_bounds__(256) void ln_kernel(
    const float* __restrict__ xin, const float* __restrict__ gamma,
    const float* __restrict__ beta, unsigned short* __restrict__ out)
{
    const int row = blockIdx.x;
    const int tid = threadIdx.x;
    const float4 v = ((const float4*)(xin + (size_t)row * Cn))[tid];
    float s  = v.x + v.y + v.z + v.w;
    float ss = v.x*v.x + v.y*v.y + v.z*v.z + v.w*v.w;
    #pragma unroll
    for (int off = 1; off < 64; off <<= 1) {
        s  += __shfl_xor(s, off);
        ss += __shfl_xor(ss, off);
    }
    __shared__ float red[8];
    const int wave = tid >> 6, lane = tid & 63;
    if (lane == 0) { red[wave] = s; red[4 + wave] = ss; }
    __syncthreads();
    float S  = red[0] + red[1] + red[2] + red[3];
    float SS = red[4] + red[5] + red[6] + red[7];
    float mean = S * (1.0f / 1024.0f);
    float var  = (SS - 1024.0f * mean * mean) * (1.0f / 1023.0f);
    var = fmaxf(var, 0.0f);
    float inv = 1.0f / (sqrtf(var) + LNEPS);
    const float4 gv = ((const float4*)gamma)[tid];
    const float4 bv = ((const float4*)beta)[tid];
    us4 ov;
    ov[0] = f2bf(gv.x * (v.x - mean) * inv + bv.x);
    ov[1] = f2bf(gv.y * (v.y - mean) * inv + bv.y);
    ov[2] = f2bf(gv.z * (v.z - mean) * inv + bv.z);
    ov[3] = f2bf(gv.w * (v.w - mean) * inv + bv.w);
    *(us4*)(out + (size_t)row * Cn + tid * 4) = ov;
}

// ---------------- GEMM: C[M][N] = A[M][K] * Bt[N][K]^T  (bf16 in, f32 acc) ----------------
// 128x128 tile, BK=32, 4 waves, 3-buffer LDS pipeline with counted vmcnt:
//   prologue: STAGE(0,buf0) STAGE(1,buf1); vmcnt(4); barrier
//   iter t:   STAGE(t+2, buf[(t+2)%3]); compute buf[t%3]; vmcnt(4); barrier
// Hazards: WAR - STAGE targets the buffer 2 ahead (distinct from both live read bufs);
//          RAW - per-wave vmcnt(4) + barrier => all waves' STAGE(t+1) landed before iter t+1 reads.
template<int MODE>
__global__ __launch_bounds__(256) void gemm_bt(
    const unsigned short* __restrict__ A,
    const unsigned short* __restrict__ Bt,
    void* Cout,                      // may alias resid (FF2) -> no restrict
    const float* __restrict__ bias,
    const float* resid,
    int M, int N, int K)
{
    __shared__ unsigned short lds[3][8192];   // per buf: A[128][32] @0, B[128][32] @4096
    const int tid  = threadIdx.x;
    const int wave = tid >> 6, lane = tid & 63;
    const int g = lane >> 4, c = lane & 15;
    const int wr = wave >> 1, wc = wave & 1;
    const int m0 = blockIdx.x * 128, n0 = blockIdx.y * 128;

    f32x4 acc[4][4];
    #pragma unroll
    for (int i = 0; i < 4; i++)
        #pragma unroll
        for (int j = 0; j < 4; j++) acc[i][j] = (f32x4){0.f, 0.f, 0.f, 0.f};

    const int srow = tid >> 2;            // 0..63
    const int scol = (tid & 3) * 8;       // elements
    const unsigned short* sA0 = A  + (size_t)(m0 + srow)      * K + scol;
    const unsigned short* sA1 = A  + (size_t)(m0 + 64 + srow) * K + scol;
    const unsigned short* sB0 = Bt + (size_t)(n0 + srow)      * K + scol;
    const unsigned short* sB1 = Bt + (size_t)(n0 + 64 + srow) * K + scol;
    const int wbase = wave * 512;         // per-wave dest base (elements)

    auto STAGE = [&](int t, int b) {
        const int ko = t * 32;
        unsigned short* L = &lds[b][0];
        gl_lds16(sA0 + ko, L + wbase);
        gl_lds16(sA1 + ko, L + 2048 + wbase);
        gl_lds16(sB0 + ko, L + 4096 + wbase);
        gl_lds16(sB1 + ko, L + 6144 + wbase);
    };

    STAGE(0, 0);
    STAGE(1, 1);
    asm volatile("s_waitcnt vmcnt(4)" ::: "memory");
    __builtin_amdgcn_s_barrier();

    const int NT = K >> 5;
    int cur = 0;
    for (int t = 0; t < NT; ++t) {
        const bool pf = (t + 2 < NT);
        if (pf) { int b = cur + 2; if (b >= 3) b -= 3; STAGE(t + 2, b); }

        bf16x8 af[4], bfr[4];
        #pragma unroll
        for (int mi = 0; mi < 4; mi++)
            af[mi]  = *(const bf16x8*)&lds[cur][(wr * 64 + mi * 16 + c) * 32 + g * 8];
        #pragma unroll
        for (int ni = 0; ni < 4; ni++)
            bfr[ni] = *(const bf16x8*)&lds[cur][4096 + (wc * 64 + ni * 16 + c) * 32 + g * 8];
        __builtin_amdgcn_s_setprio(1);
        #pragma unroll
        for (int mi = 0; mi < 4; mi++)
            #pragma unroll
            for (int ni = 0; ni < 4; ni++)
                acc[mi][ni] = __builtin_amdgcn_mfma_f32_16x16x32_bf16(
                    af[mi], bfr[ni], acc[mi][ni], 0, 0, 0);
        __builtin_amdgcn_s_setprio(0);

        if (pf) asm volatile("s_waitcnt vmcnt(4)" ::: "memory");
        else    asm volatile("s_waitcnt vmcnt(0)" ::: "memory");
        __builtin_amdgcn_s_barrier();
        cur = (cur == 2) ? 0 : cur + 1;
    }

    const int rowb = m0 + wr * 64 + g * 4;
    const int colb = n0 + wc * 64 + c;
    #pragma unroll
    for (int mi = 0; mi < 4; mi++) {
        #pragma unroll
        for (int ni = 0; ni < 4; ni++) {
            const int col = colb + ni * 16;
            float bv = (MODE == 1 || MODE == 2) ? bias[col] : 0.f;
            #pragma unroll
            for (int r = 0; r < 4; r++) {
                const int row = rowb + mi * 16 + r;
                float v = acc[mi][ni][r];
                if (MODE == 1) {
                    float res = resid[(size_t)row * N + col];
                    ((float*)Cout)[(size_t)row * N + col] = v + bv + res;
                } else if (MODE == 2) {
                    float t = v + bv;
                    t = t > 0.f ? t : 0.f;
                    ((unsigned short*)Cout)[(size_t)row * N + col] = f2bf(t);
                } else {
                    ((unsigned short*)Cout)[(size_t)row * N + col] = f2bf(v);
                }
            }
        }
    }
}

// ---------------- V transpose: qkv v-part [b][t][h*64+d] -> vt[bh][d][t] ----------------
__global__ __launch_bounds__(256) void transpose_v_kernel(
    const unsigned short* __restrict__ qkv, unsigned short* __restrict__ vt)
{
    __shared__ unsigned short tile[64][72];
    const int bh = blockIdx.y;
    const int b = bh >> 4, h = bh & 15;
    const int t0 = blockIdx.x * 64;
    const int tid = threadIdx.x;
    const int tr = tid >> 2;
    const int dc = (tid & 3) * 16;
    const unsigned short* src =
        qkv + (size_t)(b * Tn + t0 + tr) * 3072 + 2048 + h * 64 + dc;
    *(us8*)&tile[tr][dc]     = *(const us8*)src;
    *(us8*)&tile[tr][dc + 8] = *(const us8*)(src + 8);
    __syncthreads();
    const int dr = tid >> 2;
    const int tc = (tid & 3) * 16;
    unsigned short* dst = vt + (size_t)bh * Hn * Tn + (size_t)dr * Tn + t0 + tc;
    us8 o0, o1;
    #pragma unroll
    for (int e = 0; e < 8; e++) o0[e] = tile[tc + e][dr];
    #pragma unroll
    for (int e = 0; e < 8; e++) o1[e] = tile[tc + 8 + e][dr];
    *(us8*)dst       = o0;
    *(us8*)(dst + 8) = o1;
}

// ---------------- flash attention (swapped QK^T, no LDS, QBLK=32 KVBLK=64) ----------------
// Softmax in log2 domain: S_scaled = S * (0.125*log2e); exp2f everywhere (saves v_mul chain).
__global__ __launch_bounds__(256, 2) void attn_kernel(
    const unsigned short* __restrict__ qkv,
    const unsigned short* __restrict__ vt,
    unsigned short* __restrict__ ctx)
{
    const float SCL = 0.125f * 1.44269504088896f;
    const int tid  = threadIdx.x;
    const int wave = tid >> 6, lane = tid & 63;
    const int g = lane >> 4, c = lane & 15;
    const int bx = blockIdx.x;                                  // 0..15
    const int tileIdx = wave * 16 + ((wave & 1) ? (15 - bx) : bx); // balanced pairing
    const int t0 = tileIdx * 32;
    const int bh = blockIdx.y;
    const int b = bh >> 4, h = bh & 15;
    const unsigned short* base  = qkv + (size_t)b * Tn * 3072;
    const unsigned short* qbase = base + h * 64;
    const unsigned short* kbase = base + 1024 + h * 64;
    const unsigned short* vtb   = vt + (size_t)bh * (Hn * Tn);

    bf16x8 qf[2][2];
    #pragma unroll
    for (int qa = 0; qa < 2; qa++) {
        const unsigned short* qp = qbase + (size_t)(t0 + qa * 16 + c) * 3072 + g * 8;
        qf[qa][0] = *(const bf16x8*)qp;
        qf[qa][1] = *(const bf16x8*)(qp + 32);
    }

    float mrun[2] = {-1e30f, -1e30f};
    float lrun[2] = {0.f, 0.f};
    f32x4 o[2][4];
    #pragma unroll
    for (int qa = 0; qa < 2; qa++)
        #pragma unroll
        for (int nc = 0; nc < 4; nc++) o[qa][nc] = (f32x4){0.f, 0.f, 0.f, 0.f};

    for (int s0 = 0; s0 < t0 + 32; s0 += 64) {
        bf16x8 kf[4][2];
        #pragma unroll
        for (int sc = 0; sc < 4; sc++) {
            const unsigned short* kp = kbase + (size_t)(s0 + sc * 16 + c) * 3072 + g * 8;
            kf[sc][0] = *(const bf16x8*)kp;
            kf[sc][1] = *(const bf16x8*)(kp + 32);
        }
        bf16x8 vf[4][2];
        #pragma unroll
        for (int nc = 0; nc < 4; nc++)
            #pragma unroll
            for (int ks = 0; ks < 2; ks++)
                vf[nc][ks] = *(const bf16x8*)(vtb + (size_t)(nc * 16 + c) * Tn
                                              + s0 + ks * 32 + g * 8);

        // S^T = K·Q^T : lane(g,c) -> S[q=c (tile qa)][s = sc*16 + 4g + r]
        f32x4 sacc[2][4];
        #pragma unroll
        for (int qa = 0; qa < 2; qa++)
            #pragma unroll
            for (int sc = 0; sc < 4; sc++) {
                f32x4 z = (f32x4){0.f, 0.f, 0.f, 0.f};
                z = __builtin_amdgcn_mfma_f32_16x16x32_bf16(kf[sc][0], qf[qa][0], z, 0, 0, 0);
                z = __builtin_amdgcn_mfma_f32_16x16x32_bf16(kf[sc][1], qf[qa][1], z, 0, 0, 0);
                sacc[qa][sc] = z;
            }

        uint32_t dw[2][4][2];
        #pragma unroll
        for (int qa = 0; qa < 2; qa++) {
            const int q = t0 + qa * 16 + c;
            float pm[4][4];
            const bool needMask = (s0 + 63 > t0 + qa * 16);
            #pragma unroll
            for (int sc = 0; sc < 4; sc++)
                #pragma unroll
                for (int r = 0; r < 4; r++) {
                    float v = sacc[qa][sc][r] * SCL;
                    if (needMask && (s0 + sc * 16 + 4 * g + r > q)) v = -1e30f;
                    pm[sc][r] = v;
                }
            float tmax = pm[0][0];
            #pragma unroll
            for (int sc = 0; sc < 4; sc++)
                #pragma unroll
                for (int r = 0; r < 4; r++) tmax = fmaxf(tmax, pm[sc][r]);
            tmax = fmaxf(tmax, __shfl_xor(tmax, 16));
            tmax = fmaxf(tmax, __shfl_xor(tmax, 32));
            float mnew = fmaxf(mrun[qa], tmax);
            float corr = exp2f(mrun[qa] - mnew);
            mrun[qa] = mnew;
            float csum = 0.f;
            #pragma unroll
            for (int sc = 0; sc < 4; sc++)
                #pragma unroll
                for (int r = 0; r < 4; r++) {
                    float p = exp2f(pm[sc][r] - mnew);
                    pm[sc][r] = p;
                    csum += p;
                }
            csum += __shfl_xor(csum, 16);
            csum += __shfl_xor(csum, 32);
            lrun[qa] = lrun[qa] * corr + csum;
            float cb[4];
            #pragma unroll
            for (int r = 0; r < 4; r++) cb[r] = __shfl(corr, 4 * g + r);
            #pragma unroll
            for (int nc = 0; nc < 4; nc++)
                #pragma unroll
                for (int r = 0; r < 4; r++) o[qa][nc][r] *= cb[r];
            #pragma unroll
            for (int sc = 0; sc < 4; sc++) {
                dw[qa][sc][0] = pk2bf(pm[sc][0], pm[sc][1]);
                dw[qa][sc][1] = pk2bf(pm[sc][2], pm[sc][3]);
            }
        }

        // Redistribute P^T -> PV A-frag (see derivation): src lane (2(g&1)+jh)*16+c
        #pragma unroll
        for (int ks = 0; ks < 2; ks++) {
            #pragma unroll
            for (int qa = 0; qa < 2; qa++) {
                u32x4 pd;
                #pragma unroll
                for (int jh = 0; jh < 2; jh++) {
                    const int srcLane = (2 * (g & 1) + jh) * 16 + c;
                    #pragma unroll
                    for (int hh = 0; hh < 2; hh++) {
                        int vA = __shfl((int)dw[qa][2 * ks][hh],     srcLane);
                        int vB = __shfl((int)dw[qa][2 * ks + 1][hh], srcLane);
                        pd[jh * 2 + hh] = (g < 2) ? (uint32_t)vA : (uint32_t)vB;
                    }
                }
                bf16x8 pa = __builtin_bit_cast(bf16x8, pd);
                #pragma unroll
                for (int nc = 0; nc < 4; nc++)
                    o[qa][nc] = __builtin_amdgcn_mfma_f32_16x16x32_bf16(
                        pa, vf[nc][ks], o[qa][nc], 0, 0, 0);
            }
        }
    }

    #pragma unroll
    for (int qa = 0; qa < 2; qa++) {
        float rl = 1.0f / lrun[qa];
        float lb[4];
        #pragma unroll
        for (int r = 0; r < 4; r++) lb[r] = __shfl(rl, 4 * g + r);
        #pragma unroll
        for (int nc = 0; nc < 4; nc++)
            #pragma unroll
            for (int r = 0; r < 4; r++) {
                const int trow = t0 + qa * 16 + 4 * g + r;
                ctx[(size_t)(b * Tn + trow) * 1024 + h * 64 + nc * 16 + c] =
                    f2bf(o[qa][nc][r] * lb[r]);
            }
    }
}

// ---------------- launch ----------------
extern "C" void kernel_launch(void* const* d_in, const int* in_sizes, int n_in,
                              void* d_out, int out_size, void* d_ws, size_t ws_size,
                              hipStream_t stream) {
    const float* x   = (const float*)d_in[0];
    const float* Wq  = (const float*)d_in[1];
    const float* Wk  = (const float*)d_in[2];
    const float* Wv  = (const float*)d_in[3];
    const float* Wo  = (const float*)d_in[4];
    const float* bo  = (const float*)d_in[5];
    const float* W1  = (const float*)d_in[6];
    const float* b1  = (const float*)d_in[7];
    const float* W2  = (const float*)d_in[8];
    const float* b2  = (const float*)d_in[9];
    const float* g1  = (const float*)d_in[10];
    const float* be1 = (const float*)d_in[11];
    const float* g2  = (const float*)d_in[12];
    const float* be2 = (const float*)d_in[13];

    char* ws = (char*)d_ws;
    unsigned short* wqkv = (unsigned short*)ws;  ws += (size_t)3072 * 1024 * 2;
    unsigned short* wo   = (unsigned short*)ws;  ws += (size_t)1024 * 1024 * 2;
    unsigned short* w1   = (unsigned short*)ws;  ws += (size_t)3072 * 1024 * 2;
    unsigned short* w2   = (unsigned short*)ws;  ws += (size_t)1024 * 3072 * 2;
    unsigned short* bufA = (unsigned short*)ws;  ws += (size_t)Mrows * 1024 * 2; // xn1 / ctx / h2
    unsigned short* bufB = (unsigned short*)ws;  ws += (size_t)Mrows * 3072 * 2; // qkv / ffh

    float* xout = (float*)d_out;           // x1 lives here after out-proj
    unsigned short* vt = (unsigned short*)d_out;   // V^T parks in dead d_out

    // weight prep
    cast_qkv_kernel<<<12288, 256, 0, stream>>>(Wq, Wk, Wv, wqkv);
    cast_w_kernel<<<4096, 256, 0, stream>>>(Wo, wo, 1024 * 1024);
    cast_w_kernel<<<12288, 256, 0, stream>>>(W1, w1, 3072 * 1024);
    cast_w_kernel<<<12288, 256, 0, stream>>>(W2, w2, 1024 * 3072);

    // xn1 = LN(x)
    ln_kernel<<<Mrows, 256, 0, stream>>>(x, g1, be1, bufA);
    // qkv = xn1 @ Wqkv^T
    gemm_bt<0><<<dim3(32, 24), 256, 0, stream>>>(bufA, wqkv, bufB, nullptr, nullptr,
                                                 Mrows, 3072, 1024);
    // vt = V^T
    transpose_v_kernel<<<dim3(Tn / 64, 2 * NHn), 256, 0, stream>>>(bufB, vt);
    // ctx = attention(qkv, vt)
    attn_kernel<<<dim3(16, 2 * NHn), 256, 0, stream>>>(bufB, vt, bufA);
    // x1 = x + ctx @ Wo^T + bo   (f32, into d_out; vt dead afterwards)
    gemm_bt<1><<<dim3(32, 8), 256, 0, stream>>>(bufA, wo, xout, bo, x,
                                                Mrows, 1024, 1024);
    // h2 = LN(x1)
    ln_kernel<<<Mrows, 256, 0, stream>>>(xout, g2, be2, bufA);
    // ffh = relu(h2 @ W1^T + b1)
    gemm_bt<2><<<dim3(32, 24), 256, 0, stream>>>(bufA, w1, bufB, b1, nullptr,
                                                 Mrows, 3072, 1024);
    // out = x1 + ffh @ W2^T + b2  (in-place residual from d_out)
    gemm_bt<1><<<dim3(32, 8), 256, 0, stream>>>(bufB, w2, xout, b2, (const float*)xout,
                                                Mrows, 1024, 3072);
}